// Round 3
// baseline (116.615 us; speedup 1.0000x reference)
//
#include <hip/hip_runtime.h>

#define KCODES 512
#define DDIM   64
#define NPIX   1024                      // 32*32 spatial per batch
#define QELEMS (64 * DDIM * NPIX)        // 4194304

// Bit-exact emulation of the numpy fp32 reference:
//   x2[n]   = seq-over-d sum of fl(x_d^2)
//   w2[k]   = seq-over-d sum of fl(w_dk^2)
//   dot[nk] = seq-over-d sum of fl(x_d * w_dk)      (mul+add, NO fma)
//   dist    = fl( fl(x2 - fl(2*dot)) + w2 )
//   argmin  = first (lowest-k) minimum
__global__ __launch_bounds__(256) void vq_kernel(
    const float* __restrict__ x, const float* __restrict__ w,
    float* __restrict__ qout, float* __restrict__ aout) {
#pragma clang fp contract(off)

  __shared__ float  xs[DDIM][64];        // 16 KB x tile [d][pixel]
  __shared__ float  w2f[KCODES];         //  2 KB fp32 ||w_k||^2 (np-ordered)
  __shared__ float  sm1[4][64];
  __shared__ int    si1[4][64];
  __shared__ int    skm[64];

  const int tid  = threadIdx.x;
  const int lane = tid & 63;
  const int wid  = __builtin_amdgcn_readfirstlane(tid >> 6);  // wave id, uniform
  const int b    = blockIdx.x >> 4;
  const int n0   = (blockIdx.x & 15) << 6;
  const size_t pixbase = (size_t)blockIdx.x << 6;

  // ---- stage x tile into LDS (coalesced 64-lane rows) ----
  {
    const float* xp = x + (size_t)b * (DDIM * NPIX) + n0;
#pragma unroll
    for (int dd = 0; dd < 16; ++dd) {
      int d = dd * 4 + wid;
      xs[d][lane] = xp[(size_t)d * NPIX + lane];
    }
  }

  // ---- w2 in fp32, sequential over d (numpy order), per block ----
#pragma unroll
  for (int kk = 0; kk < 2; ++kk) {
    int k = tid + kk * 256;
    float s = 0.0f;
    for (int d = 0; d < DDIM; ++d) {
      float v = w[d * KCODES + k];
      float p = v * v;                   // rounded product
      s = s + p;                         // rounded add, d ascending
    }
    w2f[k] = s;
  }
  __syncthreads();

  // ---- x2 per pixel, fp32 sequential over d (numpy order) ----
  float x2 = 0.0f;
#pragma unroll
  for (int d = 0; d < DDIM; ++d) {
    float xv = xs[d][lane];
    float p = xv * xv;
    x2 = x2 + p;
  }

  // ---- fp32 emulated path: wave `wid` owns k in [wid*128, wid*128+128) ----
  float m1 = 3.4e38f;
  int   i1 = 0;
  const int kbase = wid * 128;

  for (int kt = 0; kt < 8; ++kt) {
    const int k0 = kbase + kt * 16;
    float acc[16];
#pragma unroll
    for (int j = 0; j < 16; ++j) acc[j] = 0.f;

#pragma unroll
    for (int d = 0; d < DDIM; ++d) {
      // wave-uniform address -> scalar loads
      const float4* wr = reinterpret_cast<const float4*>(w + d * KCODES + k0);
      float4 w0 = wr[0];
      float4 w1 = wr[1];
      float4 w2v = wr[2];
      float4 w3 = wr[3];
      float xv = xs[d][lane];
      // separate mul + add (contract off) to match numpy einsum rounding
      float p0  = xv * w0.x;  acc[0]  = acc[0]  + p0;
      float p1  = xv * w0.y;  acc[1]  = acc[1]  + p1;
      float p2  = xv * w0.z;  acc[2]  = acc[2]  + p2;
      float p3  = xv * w0.w;  acc[3]  = acc[3]  + p3;
      float p4  = xv * w1.x;  acc[4]  = acc[4]  + p4;
      float p5  = xv * w1.y;  acc[5]  = acc[5]  + p5;
      float p6  = xv * w1.z;  acc[6]  = acc[6]  + p6;
      float p7  = xv * w1.w;  acc[7]  = acc[7]  + p7;
      float p8  = xv * w2v.x; acc[8]  = acc[8]  + p8;
      float p9  = xv * w2v.y; acc[9]  = acc[9]  + p9;
      float p10 = xv * w2v.z; acc[10] = acc[10] + p10;
      float p11 = xv * w2v.w; acc[11] = acc[11] + p11;
      float p12 = xv * w3.x;  acc[12] = acc[12] + p12;
      float p13 = xv * w3.y;  acc[13] = acc[13] + p13;
      float p14 = xv * w3.z;  acc[14] = acc[14] + p14;
      float p15 = xv * w3.w;  acc[15] = acc[15] + p15;
    }

#pragma unroll
    for (int j = 0; j < 16; ++j) {
      float tdm = 2.0f * acc[j];         // exact (*2)
      float t   = x2 - tdm;              // rounds at ulp(~64) — the decisive grid
      float s   = t + w2f[k0 + j];       // rounds
      bool lt = s < m1;                  // strict: first minimum wins (lowest k)
      m1 = lt ? s : m1;
      i1 = lt ? (k0 + j) : i1;
    }
  }

  sm1[wid][lane] = m1;
  si1[wid][lane] = i1;
  __syncthreads();

  // ---- merge 4 waves (ascending k ranges; strict < keeps lowest k on ties) ----
  if (tid < 64) {
    float M1 = sm1[0][lane];
    int   I1 = si1[0][lane];
#pragma unroll
    for (int c = 1; c < 4; ++c) {
      float c1 = sm1[c][lane];
      if (c1 < M1) { M1 = c1; I1 = si1[c][lane]; }
    }
    skm[lane] = I1;
    aout[pixbase + lane] = (float)I1;
  }
  __syncthreads();

  // ---- quantized write: 256 threads, each 16 d-rows, coalesced along n ----
  const int kmin = skm[lane];
  float* qp = qout + (size_t)b * (DDIM * NPIX) + n0 + lane;
#pragma unroll
  for (int dd = 0; dd < 16; ++dd) {
    int d = wid * 16 + dd;
    qp[(size_t)d * NPIX] = w[d * KCODES + kmin];
  }
}

extern "C" void kernel_launch(void* const* d_in, const int* in_sizes, int n_in,
                              void* d_out, int out_size, void* d_ws, size_t ws_size,
                              hipStream_t stream) {
  const float* x = (const float*)d_in[0];
  const float* w = (const float*)d_in[1];
  float* qout = (float*)d_out;
  float* aout = (float*)d_out + QELEMS;

  vq_kernel<<<64 * 16, 256, 0, stream>>>(x, w, qout, aout);
}